// Round 3
// baseline (211.101 us; speedup 1.0000x reference)
//
#include <hip/hip_runtime.h>
#include <hip/hip_bf16.h>
#include <stdint.h>

typedef unsigned short u16;
typedef __attribute__((ext_vector_type(8))) short short8;
typedef __attribute__((ext_vector_type(4))) float f32x4;

#define BATCH 4096
#define DIN   1024
#define NH    1024
#define KTOT  2048

__device__ __forceinline__ void gload_lds16(const void* gp, void* lp) {
    __builtin_amdgcn_global_load_lds(
        (const __attribute__((address_space(1))) uint32_t*)gp,
        (__attribute__((address_space(3))) uint32_t*)lp, 16, 0, 0);
}

__device__ __forceinline__ u16 f2bf(float f) {   // round-to-nearest-even
    uint32_t t; __builtin_memcpy(&t, &f, 4);
    uint32_t r = (t + 0x7FFFu + ((t >> 16) & 1u)) >> 16;
    return (u16)r;
}
__device__ __forceinline__ float hsig(float z) {
    return fminf(fmaxf(fmaf(z, 0.2f, 0.5f), 0.0f), 1.0f);
}
__device__ __forceinline__ float fast_tanh(float x) {
    x = fminf(fmaxf(x, -12.0f), 12.0f);
    float e = __expf(2.0f * x);
    return (e - 1.0f) / (e + 1.0f);
}

// ---------------------------------------------------------------------------
// Fused prep kernel (unchanged):
//   blocks [0, 2048):      weight cast+transpose+concat -> Bt[(g*NH+n)][KTOT]
//   blocks [2048, 18432):  activation cast+concat       -> Abuf[m][KTOT]
// ---------------------------------------------------------------------------
#define WT_BLOCKS 2048
__global__ __launch_bounds__(256) void prep_kernel(
    const float* __restrict__ x, const float* __restrict__ h0,
    const float* __restrict__ Wf, const float* __restrict__ Wi,
    const float* __restrict__ Wo, const float* __restrict__ Wc,
    const float* __restrict__ Uf, const float* __restrict__ Ui,
    const float* __restrict__ Uo, const float* __restrict__ Uc,
    u16* __restrict__ Bt, u16* __restrict__ Abuf)
{
    __shared__ u16 tile[64][65];
    const int bid = blockIdx.x;
    const int tid = threadIdx.x;

    if (bid < WT_BLOCKS) {
        const int mz = bid >> 8;
        const float* srcs[8] = {Wf, Wi, Wo, Wc, Uf, Ui, Uo, Uc};
        const float* src = srcs[mz];
        const int g    = mz & 3;
        const int koff = (mz >> 2) << 10;
        const int k0 = ((bid >> 4) & 15) * 64;
        const int n0 = (bid & 15) * 64;

#pragma unroll
        for (int i = 0; i < 4; i++) {
            int idx = i * 256 + tid;
            int kk = idx >> 4, c = idx & 15;
            float4 v = *(const float4*)(src + (size_t)(k0 + kk) * NH + n0 + c * 4);
            u16* dst = &tile[kk][c * 4];
            dst[0] = f2bf(v.x); dst[1] = f2bf(v.y);
            dst[2] = f2bf(v.z); dst[3] = f2bf(v.w);
        }
        __syncthreads();
#pragma unroll
        for (int i = 0; i < 2; i++) {
            int idx = i * 256 + tid;
            int nn = idx >> 3, c = idx & 7;
            union { u16 v[8]; uint4 q; } pk;
#pragma unroll
            for (int j = 0; j < 8; j++) pk.v[j] = tile[c * 8 + j][nn];
            *(uint4*)(Bt + ((size_t)(g * NH + n0 + nn)) * KTOT + koff + k0 + c * 8) = pk.q;
        }
    } else {
        const int c  = (bid - WT_BLOCKS) * 256 + tid;
        const int m  = c >> 8;
        const int kc = (c & 255) * 8;
        const float* src = (kc < DIN) ? (x + (size_t)m * DIN + kc)
                                      : (h0 + (size_t)m * DIN + (kc - DIN));
        float4 v0 = *(const float4*)(src);
        float4 v1 = *(const float4*)(src + 4);
        union { u16 v[8]; uint4 q; } pk;
        pk.v[0] = f2bf(v0.x); pk.v[1] = f2bf(v0.y);
        pk.v[2] = f2bf(v0.z); pk.v[3] = f2bf(v0.w);
        pk.v[4] = f2bf(v1.x); pk.v[5] = f2bf(v1.y);
        pk.v[6] = f2bf(v1.z); pk.v[7] = f2bf(v1.w);
        *(uint4*)(Abuf + (size_t)m * KTOT + kc) = pk.q;
    }
}

// ---------------------------------------------------------------------------
// R13 GEMM: m201-template 8-phase port.  256m x (64n x 4g) block, BK=64,
// 2-buffer LDS (2 x 64 KB), 8 waves (2m x 4n), acc[8][4] (128m x 16n x 4g
// per wave).  4 phases/K-tile, quadrant order (hm,hg) = (0,0),(0,1),(1,1),
// (1,0): A-frags reused across the hg pair, both B-frag sets stay live ->
// 24 ds_read_b128 / wave / tile (phase reads: 12,4,8,0).
// Phase: [ds_reads | stage 1 half-tile (2 gload_lds)] -> s_barrier ->
//        lgkmcnt(0) -> sched_barrier(0) -> setprio(1) 16 MFMA setprio(0)
//        -> [counted vmcnt] -> s_barrier.
// Stage order per tile: H0=A-lo, H1=A-hi, H2=B-lo(g0,g1), H3=B-hi(g2,g3);
// tile t+1 staged into buf[(t+1)&1] during tile t (its last readers were
// tile t-1, whose lgkm waits precede t-1's trailing barriers).
// vmcnt ledger (2 loads/half/wave, waits BEFORE a barrier so per-wave
// vmcnt => all-waves guarantee after the barrier):
//   end p3(t): outstanding = H0..H3(t+1) (8) -> vmcnt(2): H0,H1,H2 landed
//              (needed by p0(t+1) reads: A-lo, A-hi, B-lo).
//   end p0(t): outstanding = H3(t), H0(t+1) (4) -> vmcnt(2): H3(t) landed
//              (needed by p1(t) reads: B-hi).   Never drained to 0 in-loop.
// LDS swizzle: 128-B rows, 8 x 16-B chunks; phys chunk = logical ^ (row&7),
// applied on the pre-swizzled GLOBAL source (gload_lds writes linearly) and
// on the ds_read side.  Frag reads: per quad 16 lanes hit 8 chunk slots
// 2-way (rows +-8) -> free (m136).
// ---------------------------------------------------------------------------
#define BM   256
#define BNG  64                 // n-cols per gate per block
#define BK   64
#define NT   (KTOT / BK)        // 32 K-tiles
#define AT_ELEMS (BM * BK)      // 16384 u16 = 32 KB (one matrix, one tile)
#define BUF_ELEMS (2 * AT_ELEMS) // A + B per buffer

__global__ __launch_bounds__(512, 2) void lstm_gemm_kernel(
    const u16* __restrict__ Abuf, const float* __restrict__ c0,
    const u16* __restrict__ Bt,
    const float* __restrict__ bfv, const float* __restrict__ biv,
    const float* __restrict__ bov, const float* __restrict__ bcv,
    float* __restrict__ out)
{
    extern __shared__ u16 smem[];            // 128 KiB dynamic LDS

    const int tid  = threadIdx.x;
    const int wv   = tid >> 6;
    const int lane = tid & 63;
    const int wm = wv >> 2;                  // 0..1  (m half)
    const int wn = wv & 3;                   // 0..3  (16-col slice per gate)
    const int m0 = blockIdx.x * BM;
    const int n0 = blockIdx.y * BNG;

    // ---- staging constants (per-wave: 1 KB per gload issue, 2 per half) --
    const int l8   = lane >> 3;                       // 0..7
    const int sc   = ((lane & 7) ^ l8) * 8;           // pre-swizzled chunk
    const int rowL = wv * 8 + l8;                     // 0..63
    const u16* gA = Abuf + (size_t)(m0 + rowL) * KTOT + sc;
    const u16* gB = Bt   + (size_t)(n0 + rowL) * KTOT + sc;   // gate 0 row
    u16* ldsW = smem + wv * 512;

    // ---- fragment constants ----
    const int am   = lane & 15;
    const int quad = lane >> 4;
    const int a7   = am & 7;
    const int ck0 = (quad ^ a7) * 8;          // k-chunk, kk=0 (un-swizzled)
    const int ck1 = ((4 + quad) ^ a7) * 8;    // kk=1
    int rA[8], rB[4];
#pragma unroll
    for (int mt = 0; mt < 8; mt++) rA[mt] = (wm * 128 + mt * 16 + am) * BK;
#pragma unroll
    for (int g = 0; g < 4; g++)    rB[g]  = (g * 64 + wn * 16 + am) * BK;

    f32x4 acc[8][4];
#pragma unroll
    for (int mt = 0; mt < 8; mt++)
#pragma unroll
        for (int g = 0; g < 4; g++)
            acc[mt][g] = (f32x4){0.f, 0.f, 0.f, 0.f};

    // half: 0=A-lo 1=A-hi 2=B-lo 3=B-hi; each = 2 gload issues (rounds +64 rows)
    auto stageHalf = [&](int half, int tt) {
        u16* ld = ldsW + (size_t)(tt & 1) * BUF_ELEMS + half * 8192;
        const size_t ko = (size_t)tt * BK;
        if (half == 0) {
            gload_lds16(gA + ko, ld);
            gload_lds16(gA + ko + (size_t)64 * KTOT, ld + 4096);
        } else if (half == 1) {
            const u16* g = gA + (size_t)128 * KTOT + ko;
            gload_lds16(g, ld);
            gload_lds16(g + (size_t)64 * KTOT, ld + 4096);
        } else if (half == 2) {
            gload_lds16(gB + ko, ld);
            gload_lds16(gB + ko + (size_t)NH * KTOT, ld + 4096);
        } else {
            const u16* g = gB + (size_t)2 * NH * KTOT + ko;
            gload_lds16(g, ld);
            gload_lds16(g + (size_t)NH * KTOT, ld + 4096);
        }
    };

    auto processTile = [&](int t, bool stageNext, bool last) {
        const u16* asp = smem + (t & 1) * BUF_ELEMS;
        const u16* bsp = asp + AT_ELEMS;
        short8 fa[4][2], fbL[2][2], fbH[2][2];

        // ======== phase 0: quadrant (hm=0, hg=0) ========
#pragma unroll
        for (int mt = 0; mt < 4; mt++) {
            fa[mt][0] = *(const short8*)(asp + rA[mt] + ck0);
            fa[mt][1] = *(const short8*)(asp + rA[mt] + ck1);
        }
#pragma unroll
        for (int g = 0; g < 2; g++) {
            fbL[g][0] = *(const short8*)(bsp + rB[g] + ck0);
            fbL[g][1] = *(const short8*)(bsp + rB[g] + ck1);
        }
        if (stageNext) stageHalf(0, t + 1);
        __builtin_amdgcn_s_barrier();
        asm volatile("s_waitcnt lgkmcnt(0)");
        __builtin_amdgcn_sched_barrier(0);
        __builtin_amdgcn_s_setprio(1);
#pragma unroll
        for (int g = 0; g < 2; g++)
#pragma unroll
            for (int mt = 0; mt < 4; mt++)
#pragma unroll
                for (int kk = 0; kk < 2; kk++)
                    acc[mt][g] = __builtin_amdgcn_mfma_f32_16x16x32_bf16(
                        fa[mt][kk], fbL[g][kk], acc[mt][g], 0, 0, 0);
        __builtin_amdgcn_s_setprio(0);
        if (last) asm volatile("s_waitcnt vmcnt(0)");   // H3(t): last tile
        else      asm volatile("s_waitcnt vmcnt(2)");   // H3(t) landed
        __builtin_amdgcn_s_barrier();

        // ======== phase 1: quadrant (hm=0, hg=1) ========
#pragma unroll
        for (int g = 0; g < 2; g++) {
            fbH[g][0] = *(const short8*)(bsp + rB[2 + g] + ck0);
            fbH[g][1] = *(const short8*)(bsp + rB[2 + g] + ck1);
        }
        if (stageNext) stageHalf(1, t + 1);
        __builtin_amdgcn_s_barrier();
        asm volatile("s_waitcnt lgkmcnt(0)");
        __builtin_amdgcn_sched_barrier(0);
        __builtin_amdgcn_s_setprio(1);
#pragma unroll
        for (int g = 0; g < 2; g++)
#pragma unroll
            for (int mt = 0; mt < 4; mt++)
#pragma unroll
                for (int kk = 0; kk < 2; kk++)
                    acc[mt][2 + g] = __builtin_amdgcn_mfma_f32_16x16x32_bf16(
                        fa[mt][kk], fbH[g][kk], acc[mt][2 + g], 0, 0, 0);
        __builtin_amdgcn_s_setprio(0);
        __builtin_amdgcn_s_barrier();

        // ======== phase 2: quadrant (hm=1, hg=1) ========
#pragma unroll
        for (int mt = 0; mt < 4; mt++) {
            fa[mt][0] = *(const short8*)(asp + rA[4 + mt] + ck0);
            fa[mt][1] = *(const short8*)(asp + rA[4 + mt] + ck1);
        }
        if (stageNext) stageHalf(2, t + 1);
        __builtin_amdgcn_s_barrier();
        asm volatile("s_waitcnt lgkmcnt(0)");
        __builtin_amdgcn_sched_barrier(0);
        __builtin_amdgcn_s_setprio(1);
#pragma unroll
        for (int g = 0; g < 2; g++)
#pragma unroll
            for (int mt = 0; mt < 4; mt++)
#pragma unroll
                for (int kk = 0; kk < 2; kk++)
                    acc[4 + mt][2 + g] = __builtin_amdgcn_mfma_f32_16x16x32_bf16(
                        fa[mt][kk], fbH[g][kk], acc[4 + mt][2 + g], 0, 0, 0);
        __builtin_amdgcn_s_setprio(0);
        __builtin_amdgcn_s_barrier();

        // ======== phase 3: quadrant (hm=1, hg=0) — no reads ========
        if (stageNext) stageHalf(3, t + 1);
        __builtin_amdgcn_s_barrier();
        asm volatile("s_waitcnt lgkmcnt(0)");
        __builtin_amdgcn_sched_barrier(0);
        __builtin_amdgcn_s_setprio(1);
#pragma unroll
        for (int g = 0; g < 2; g++)
#pragma unroll
            for (int mt = 0; mt < 4; mt++)
#pragma unroll
                for (int kk = 0; kk < 2; kk++)
                    acc[4 + mt][g] = __builtin_amdgcn_mfma_f32_16x16x32_bf16(
                        fa[mt][kk], fbL[g][kk], acc[4 + mt][g], 0, 0, 0);
        __builtin_amdgcn_s_setprio(0);
        if (!last) asm volatile("s_waitcnt vmcnt(2)");  // H0,H1,H2(t+1) landed
        __builtin_amdgcn_s_barrier();
    };

    // ---- prologue: stage tile 0; H0,H1,H2 landed before first reads ----
    stageHalf(0, 0);
    stageHalf(1, 0);
    stageHalf(2, 0);
    stageHalf(3, 0);
    asm volatile("s_waitcnt vmcnt(2)");
    __builtin_amdgcn_s_barrier();

    for (int t = 0; t < NT - 1; ++t)
        processTile(t, true, false);
    processTile(NT - 1, false, true);

    // ---- epilogue: C/D layout col=lane&15, row=quad*4+reg ----
    const int col = n0 + wn * 16 + am;
    const float b0 = bfv[col], b1 = biv[col], b2 = bov[col], b3 = bcv[col];
    const size_t HN = (size_t)BATCH * NH;

#pragma unroll
    for (int mt = 0; mt < 8; mt++) {
#pragma unroll
        for (int r = 0; r < 4; r++) {
            const int row = m0 + wm * 128 + mt * 16 + quad * 4 + r;
            const size_t off = (size_t)row * NH + col;
            float zf = acc[mt][0][r] + b0;
            float zi = acc[mt][1][r] + b1;
            float zo = acc[mt][2][r] + b2;
            float zc = acc[mt][3][r] + b3;
            float fg = hsig(zf), ig = hsig(zi), og = hsig(zo);
            float ct = fast_tanh(zc);
            float cn = fg * c0[off] + ig * ct;
            float hn = og * fast_tanh(cn);
            out[off]          = hn;   // h
            out[HN + off]     = cn;   // c
            out[2 * HN + off] = hn;   // h (duplicate output)
        }
    }
}

extern "C" void kernel_launch(void* const* d_in, const int* in_sizes, int n_in,
                              void* d_out, int out_size, void* d_ws, size_t ws_size,
                              hipStream_t stream) {
    const float* x  = (const float*)d_in[0];
    const float* c0 = (const float*)d_in[1];
    const float* h0 = (const float*)d_in[2];
    const float* Wf = (const float*)d_in[3];
    const float* Wi = (const float*)d_in[4];
    const float* Wo = (const float*)d_in[5];
    const float* Wc = (const float*)d_in[6];
    const float* Uf = (const float*)d_in[7];
    const float* Ui = (const float*)d_in[8];
    const float* Uo = (const float*)d_in[9];
    const float* Uc = (const float*)d_in[10];
    const float* bf = (const float*)d_in[11];
    const float* bi = (const float*)d_in[12];
    const float* bo = (const float*)d_in[13];
    const float* bc = (const float*)d_in[14];

    u16* Bt   = (u16*)d_ws;                          // 4096 x 2048 bf16 = 16 MB
    u16* Abuf = (u16*)d_ws + (size_t)4 * NH * KTOT;  // 4096 x 2048 bf16 = 16 MB

    static bool attr_done = false;
    if (!attr_done) {
        (void)hipFuncSetAttribute((const void*)lstm_gemm_kernel,
                                  hipFuncAttributeMaxDynamicSharedMemorySize,
                                  131072);
        attr_done = true;
    }

    prep_kernel<<<WT_BLOCKS + (BATCH * KTOT / 8) / 256, 256, 0, stream>>>(
        x, h0, Wf, Wi, Wo, Wc, Uf, Ui, Uo, Uc, Bt, Abuf);

    dim3 gg(BATCH / BM, NH / BNG);   // 16 x 16 = 256 blocks, 1/CU, 8 waves/CU
    lstm_gemm_kernel<<<gg, 512, 131072, stream>>>(Abuf, c0, Bt, bf, bi, bo, bc,
                                                  (float*)d_out);
}